// Round 4
// baseline (126.225 us; speedup 1.0000x reference)
//
#include <hip/hip_runtime.h>
#include <math.h>

#define C_ 512
#define HW_ 16384
#define K_ 19
#define M_ 5
#define P_ 95
#define P2 96
#define TPX 16
#define NBLK 4096
#define HL2PI 470.49652900081467f  // 0.5 * 512 * ln(2*pi)

typedef __attribute__((ext_vector_type(8))) short short8;
typedef __attribute__((ext_vector_type(4))) float float4v;

// fp32 -> bf16 RNE, returned as raw short
static __device__ __forceinline__ short f2bf(float f) {
  unsigned u = __builtin_bit_cast(unsigned, f);
  unsigned r = (u + 0x7fffu + ((u >> 16) & 1u)) >> 16;
  return (short)r;
}

__device__ __forceinline__ float block_reduce_sum(float v, volatile float* red) {
#pragma unroll
  for (int o = 32; o; o >>= 1) v += __shfl_down(v, o);
  const int lane = threadIdx.x & 63, wv = threadIdx.x >> 6;
  if (lane == 0) red[wv] = v;
  __syncthreads();
  float r = red[0] + red[1] + red[2] + red[3];
  __syncthreads();
  return r;
}

// One block per prototype p. wbf[p][k] bf16 row-major [96][1024]:
//   k <  512: inv_var[c]          (A-operand for the v^2 half)
//   k >= 512: mu[c]*inv_var[c]    (A-operand for the v half)
// cterm[p] = -0.5*q3 - logdet - HL2PI  (fp32)
__global__ __launch_bounds__(256) void prep_kernel(
    const float* __restrict__ means, const float* __restrict__ diag,
    short* __restrict__ wbf, float* __restrict__ cterm) {
  const int p = blockIdx.x;
  const int tid = threadIdx.x;
  __shared__ float red[4];
  if (p >= P_) {  // zero-pad row 95: contributes 0, never selected in max
    for (int c = tid; c < C_; c += 256) {
      wbf[p * 1024 + c] = 0;
      wbf[p * 1024 + 512 + c] = 0;
    }
    if (tid == 0) cterm[p] = 0.f;
    return;
  }
  const float* mrow = means + (size_t)p * C_;
  const float* srow = diag + (size_t)p * C_;
  float m0 = mrow[tid], m1 = mrow[tid + 256];
  float ss = block_reduce_sum(m0 * m0 + m1 * m1, red);
  float rden = 1.f / fmaxf(sqrtf(ss), 1e-12f);  // l2_normalize(means)
  float q3 = 0.f, ld = 0.f;
#pragma unroll
  for (int t = 0; t < 2; t++) {
    int c = tid + t * 256;
    float m = mrow[c], s = srow[c];
    float mu = m * rden;
    float iv = 1.f / (s * s);
    wbf[p * 1024 + c] = f2bf(iv);
    wbf[p * 1024 + 512 + c] = f2bf(mu * iv);
    q3 += mu * mu * iv;
    ld += logf(s);
  }
  q3 = block_reduce_sum(q3, red);
  ld = block_reduce_sum(ld, red);
  if (tid == 0) cterm[p] = -0.5f * q3 - ld - HL2PI;
}

// One block = 16 pixels, 256 threads (4 waves).
// u LDS (32 KiB): 32 blocks of 1 KiB, block ks holds k in [ks*32, ks*32+32).
// Byte addr for element (k, px): (ks<<10) | (l<<4) | (j<<1), l = ((k>>3)&3)<<4 | px,
// j = k&7, XOR-swizzled by ((ks&3)<<8). B-frag read = (ks<<10)|(lane<<4) ^ swz.
__global__ __launch_bounds__(256) void main_kernel(
    const float* __restrict__ x,
    const float* __restrict__ fg, const float* __restrict__ fb,
    const float* __restrict__ mg, const float* __restrict__ mb,
    const short* __restrict__ wbf, const float* __restrict__ cterm,
    float* __restrict__ out) {
  __shared__ __align__(16) char raw[32768];  // u; later aliased as lp1/lp2
  __shared__ float red0[4 * TPX], red1[4 * TPX];
  __shared__ float meanA[TPX], rstdA[TPX], rnA[TPX], rn2A[TPX];
  __shared__ float mean2A[TPX], rstd2A[TPX];
  __shared__ float mpr[TPX * 20];

  const int tid = threadIdx.x;
  const int px = tid & 15;          // pixel
  const int part = tid >> 4;        // 16 parts x 32 channels
  const int wv = tid >> 6, lane = tid & 63;
  const int n0 = blockIdx.x * TPX;
  const int b = n0 >> 14;
  const int rem = n0 & 16383;
  const int h = rem >> 7;
  const int w0 = rem & 127;

  // ---- Pass 1: x -> registers (one HBM pass), LN stats via shfl ----
  const float* xp = x + (size_t)b * C_ * HW_ + h * 128 + w0 + px;
  const int cbase = part * 32;
  float xr[32];
#pragma unroll
  for (int i = 0; i < 32; i++) xr[i] = xp[(size_t)(cbase + i) * HW_];
  {
    float s = 0.f, q = 0.f;
#pragma unroll
    for (int i = 0; i < 32; i++) {
      s += xr[i];
      q += xr[i] * xr[i];
    }
    s += __shfl_xor(s, 16); s += __shfl_xor(s, 32);
    q += __shfl_xor(q, 16); q += __shfl_xor(q, 32);
    if (lane < 16) { red0[wv * 16 + px] = s; red1[wv * 16 + px] = q; }
  }
  __syncthreads();
  if (tid < 16) {
    float ss = 0.f, qq = 0.f;
#pragma unroll
    for (int i = 0; i < 4; i++) { ss += red0[i * 16 + tid]; qq += red1[i * 16 + tid]; }
    float mean = ss * (1.f / C_);
    float var = qq * (1.f / C_) - mean * mean;
    meanA[tid] = mean;
    rstdA[tid] = rsqrtf(var + 1e-5f);
  }
  __syncthreads();

  // ---- Pass 2: v = LN(x)*g+b, u = [v^2 | v] bf16 -> LDS, sum v^2 ----
  {
    const float mean = meanA[px], rstd = rstdA[px];
    float s2 = 0.f;
    const int swz = (part & 3) << 8;
#pragma unroll
    for (int t8 = 0; t8 < 4; t8++) {
      const int c0 = cbase + t8 * 8;
      short8 v2p, vp;
#pragma unroll
      for (int j = 0; j < 8; j++) {
        const int c = c0 + j;
        float v = (xr[t8 * 8 + j] - mean) * rstd;
        v = fmaf(v, fg[c], fb[c]);
        s2 += v * v;
        v2p[j] = f2bf(v * v);
        vp[j] = f2bf(v);
      }
      // ks1 = part (v^2 half), ks2 = 16 + part (v half); same swizzle bits
      const int a1 = ((part << 10) | (t8 << 8) | (px << 4)) ^ swz;
      *(short8*)(raw + a1) = v2p;
      *(short8*)(raw + a1 + 16384) = vp;
    }
    s2 += __shfl_xor(s2, 16); s2 += __shfl_xor(s2, 32);
    if (lane < 16) red0[wv * 16 + px] = s2;
  }
  __syncthreads();
  if (tid < 16) {
    float ss = 0.f;
#pragma unroll
    for (int i = 0; i < 4; i++) ss += red0[i * 16 + tid];
    float rn = 1.f / fmaxf(sqrtf(ss), 1e-12f);  // l2_normalize folded into epilogue
    rnA[tid] = rn;
    rn2A[tid] = rn * rn;
  }
  __syncthreads();

  // ---- MFMA: wave = (khalf = wv>>1, phalf = wv&1), 3 p-tiles each ----
  const int pbase = (wv & 1) * 3;
  const int khalf = wv >> 1;        // 0: a1 (v^2 * iv), 1: a2 (v * mu*iv)
  const int lm = lane & 15, lk = lane >> 4;
  float4v acc[3] = {};
  const short* wrow = wbf + (((pbase * 16 + lm) << 10) + (khalf << 9) + (lk << 3));
#pragma unroll 4
  for (int ksl = 0; ksl < 16; ksl++) {
    const int ks = khalf * 16 + ksl;
    short8 a0 = *(const short8*)(wrow + ksl * 32);
    short8 a1 = *(const short8*)(wrow + 16384 + ksl * 32);
    short8 a2 = *(const short8*)(wrow + 32768 + ksl * 32);
    short8 bf = *(const short8*)(raw + (((ks << 10) | (lane << 4)) ^ ((ks & 3) << 8)));
    acc[0] = __builtin_amdgcn_mfma_f32_16x16x32_bf16(a0, bf, acc[0], 0, 0, 0);
    acc[1] = __builtin_amdgcn_mfma_f32_16x16x32_bf16(a1, bf, acc[1], 0, 0, 0);
    acc[2] = __builtin_amdgcn_mfma_f32_16x16x32_bf16(a2, bf, acc[2], 0, 0, 0);
  }
  __syncthreads();  // u dead; alias raw as lp1/lp2 [16][96]
  float* lp1 = (float*)raw;
  float* lp2 = (float*)(raw + 8192);

  // both khalf groups write concurrently (disjoint buffers)
  if (khalf == 0) {
#pragma unroll
    for (int i = 0; i < 3; i++) {
      const int prow = (pbase + i) * 16 + lk * 4;
#pragma unroll
      for (int r = 0; r < 4; r++)
        lp1[lm * 96 + prow + r] = fmaf(-0.5f * rn2A[lm], acc[i][r], cterm[prow + r]);
    }
  } else {
#pragma unroll
    for (int i = 0; i < 3; i++) {
      const int prow = (pbase + i) * 16 + lk * 4;
#pragma unroll
      for (int r = 0; r < 4; r++)
        lp2[lm * 96 + prow + r] = rnA[lm] * acc[i][r];
    }
  }
  __syncthreads();

  // ---- max over M (fusing lp1+lp2 add); 304 items needs strided loop ----
  for (int idx = tid; idx < TPX * K_; idx += 256) {
    const int pxx = idx / K_;
    const int k = idx - pxx * K_;
    const float* r1 = lp1 + pxx * 96 + k * M_;
    const float* r2 = lp2 + pxx * 96 + k * M_;
    float mv = r1[0] + r2[0];
#pragma unroll
    for (int m = 1; m < M_; m++) mv = fmaxf(mv, r1[m] + r2[m]);
    mpr[pxx * 20 + k] = mv;
  }
  __syncthreads();
  // ---- LN over K (two-pass: values ~ -470, var ~ 1e-3) ----
  if (tid < 16) {
    float ss = 0.f;
    for (int k = 0; k < K_; k++) ss += mpr[tid * 20 + k];
    float m2 = ss * (1.f / K_);
    float qq = 0.f;
    for (int k = 0; k < K_; k++) {
      float d = mpr[tid * 20 + k] - m2;
      qq += d * d;
    }
    mean2A[tid] = m2;
    rstd2A[tid] = rsqrtf(qq * (1.f / K_) + 1e-5f);
  }
  __syncthreads();
  // ---- coalesced store (B,K,H,W); 304 items needs strided loop ----
  float* obase = out + ((size_t)(b * K_) * 128 + h) * 128 + w0;
  for (int idx = tid; idx < TPX * K_; idx += 256) {
    const int k = idx >> 4, pxx = idx & 15;
    float v = fmaf((mpr[pxx * 20 + k] - mean2A[pxx]) * rstd2A[pxx], mg[k], mb[k]);
    obase[(size_t)k * HW_ + pxx] = v;
  }
}

extern "C" void kernel_launch(void* const* d_in, const int* in_sizes, int n_in,
                              void* d_out, int out_size, void* d_ws, size_t ws_size,
                              hipStream_t stream) {
  const float* x = (const float*)d_in[0];
  const float* means = (const float*)d_in[1];
  const float* diag = (const float*)d_in[2];
  const float* fg = (const float*)d_in[3];
  const float* fb = (const float*)d_in[4];
  const float* mg = (const float*)d_in[5];
  const float* mb = (const float*)d_in[6];
  float* out = (float*)d_out;

  short* wbf = (short*)d_ws;                                     // 96*1024*2 B
  float* cterm = (float*)((char*)d_ws + (size_t)P2 * 1024 * 2);  // +96*4 B

  prep_kernel<<<P2, 256, 0, stream>>>(means, diag, wbf, cterm);
  main_kernel<<<NBLK, 256, 0, stream>>>(x, fg, fb, mg, mb, wbf, cterm, out);
}

// Round 5
// 97.409 us; speedup vs baseline: 1.2958x; 1.2958x over previous
//
#include <hip/hip_runtime.h>
#include <math.h>

#define C_ 512
#define HW_ 16384
#define K_ 19
#define M_ 5
#define P_ 95
#define P2 96
#define TPX 32
#define GRID_ 512
#define TILES_ 4
#define HL2PI 470.49652900081467f  // 0.5 * 512 * ln(2*pi)

typedef __attribute__((ext_vector_type(8))) short short8;
typedef __attribute__((ext_vector_type(4))) float float4v;

// fp32 -> bf16 RNE, returned as raw short
static __device__ __forceinline__ short f2bf(float f) {
  unsigned u = __builtin_bit_cast(unsigned, f);
  unsigned r = (u + 0x7fffu + ((u >> 16) & 1u)) >> 16;
  return (short)r;
}

__device__ __forceinline__ float block_reduce_sum(float v, volatile float* red) {
#pragma unroll
  for (int o = 32; o; o >>= 1) v += __shfl_down(v, o);
  const int lane = threadIdx.x & 63, wv = threadIdx.x >> 6;
  if (lane == 0) red[wv] = v;
  __syncthreads();
  float r = red[0] + red[1] + red[2] + red[3];
  __syncthreads();
  return r;
}

// One block per prototype p. wbf[p][k] bf16 row-major [96][1024]:
//   k <  512: inv_var[c];  k >= 512: mu[c]*inv_var[c]
// cterm[p] = -0.5*q3 - logdet - HL2PI  (fp32)
__global__ __launch_bounds__(256) void prep_kernel(
    const float* __restrict__ means, const float* __restrict__ diag,
    short* __restrict__ wbf, float* __restrict__ cterm) {
  const int p = blockIdx.x;
  const int tid = threadIdx.x;
  __shared__ float red[4];
  if (p >= P_) {  // zero-pad row 95: contributes 0, never selected in max
    for (int c = tid; c < C_; c += 256) {
      wbf[p * 1024 + c] = 0;
      wbf[p * 1024 + 512 + c] = 0;
    }
    if (tid == 0) cterm[p] = 0.f;
    return;
  }
  const float* mrow = means + (size_t)p * C_;
  const float* srow = diag + (size_t)p * C_;
  float m0 = mrow[tid], m1 = mrow[tid + 256];
  float ss = block_reduce_sum(m0 * m0 + m1 * m1, red);
  float rden = 1.f / fmaxf(sqrtf(ss), 1e-12f);  // l2_normalize(means)
  float q3 = 0.f, ld = 0.f;
#pragma unroll
  for (int t = 0; t < 2; t++) {
    int c = tid + t * 256;
    float m = mrow[c], s = srow[c];
    float mu = m * rden;
    float iv = 1.f / (s * s);
    wbf[p * 1024 + c] = f2bf(iv);
    wbf[p * 1024 + 512 + c] = f2bf(mu * iv);
    q3 += mu * mu * iv;
    ld += logf(s);
  }
  q3 = block_reduce_sum(q3, red);
  ld = block_reduce_sum(ld, red);
  if (tid == 0) cterm[p] = -0.5f * q3 - ld - HL2PI;
}

// Persistent: 512 blocks x 4 tiles of 32 pixels. Pipeline: tile t+1's x-loads
// are issued after tile t's MFMA A-stream; no vmem READS occur after that
// point until stats(t+1) consumes xr (all epilogue params live in LDS), so
// the loads stay outstanding across epilogue+max+LN+store.
__global__ __launch_bounds__(256) void main_kernel(
    const float* __restrict__ x,
    const float* __restrict__ fg, const float* __restrict__ fb,
    const float* __restrict__ mg, const float* __restrict__ mb,
    const short* __restrict__ wbf, const float* __restrict__ cterm,
    float* __restrict__ out) {
  __shared__ __align__(16) char raw[65536];  // u (bf16 frags); aliased as lp[32][100]
  __shared__ float red0[8 * TPX], red1[8 * TPX];
  __shared__ float meanA[TPX], rstdA[TPX], rnA[TPX], rn2A[TPX];
  __shared__ float mean2A[TPX], rstd2A[TPX];
  __shared__ float mpr[TPX * 20];
  __shared__ float fgs[C_], fbs[C_], cts[P2], mgs[K_ + 1], mbs[K_ + 1];

  const int tid = threadIdx.x;
  const int px = tid & 31, part = tid >> 5;  // 8 parts x 64 channels
  const int wv = tid >> 6, lane = tid & 63;
  const int pbase = (wv & 1) * 3;
  const int khalf = wv >> 1;  // 0: a1 (v^2*iv), 1: a2 (v*mu*iv)
  const int lm = lane & 15, lk = lane >> 4;
  const int cbase = part * 64;

  // ---- prologue: stage all small params into LDS (keeps epilogue vmem-free) ----
  for (int i = tid; i < C_; i += 256) { fgs[i] = fg[i]; fbs[i] = fb[i]; }
  if (tid < P2) cts[tid] = cterm[tid];
  if (tid < K_) { mgs[tid] = mg[tid]; mbs[tid] = mb[tid]; }

  float xr[64];
  {  // issue tile-0 x-loads
    const int n0 = blockIdx.x * TPX;
    const int b = n0 >> 14, rem = n0 & 16383, h = rem >> 7, w0 = rem & 127;
    const float* xp = x + (size_t)b * C_ * HW_ + h * 128 + w0 + px;
#pragma unroll
    for (int i = 0; i < 64; i++) xr[i] = xp[(size_t)(cbase + i) * HW_];
  }

  for (int t = 0; t < TILES_; ++t) {
    const int n0 = (blockIdx.x + GRID_ * t) * TPX;
    const int b = n0 >> 14, rem = n0 & 16383, h = rem >> 7, w0 = rem & 127;

    // ---- LN stats (consumes xr; the only vmcnt wait in the loop) ----
    {
      float s = 0.f, q = 0.f;
#pragma unroll
      for (int i = 0; i < 64; i++) {
        s += xr[i];
        q += xr[i] * xr[i];
      }
      red0[part * 32 + px] = s;
      red1[part * 32 + px] = q;
    }
    __syncthreads();
    if (tid < 32) {
      float ss = 0.f, qq = 0.f;
#pragma unroll
      for (int i = 0; i < 8; i++) {
        ss += red0[i * 32 + tid];
        qq += red1[i * 32 + tid];
      }
      float mean = ss * (1.f / C_);
      float var = qq * (1.f / C_) - mean * mean;
      meanA[tid] = mean;
      rstdA[tid] = rsqrtf(var + 1e-5f);
    }
    __syncthreads();

    // ---- pass2: v = LN(x)*g+b, u = [v^2 | v] bf16 -> LDS, sum v^2 ----
    {
      const float mean = meanA[px], rstd = rstdA[px];
      float s2 = 0.f;
      const int t_ = px >> 4;
      const int lq = px & 15;
#pragma unroll
      for (int t8 = 0; t8 < 8; t8++) {
        const int c0 = cbase + t8 * 8;
        short8 v2p, vp;
#pragma unroll
        for (int j = 0; j < 8; j++) {
          const int c = c0 + j;
          float v = (xr[t8 * 8 + j] - mean) * rstd;
          v = fmaf(v, fgs[c], fbs[c]);
          s2 += v * v;
          v2p[j] = f2bf(v * v);
          vp[j] = f2bf(v);
        }
        const int l = (((c0 >> 3) & 3) << 4) | lq;
        const int ks1 = c0 >> 5;   // k = c      (v^2 half)
        const int ks2 = 16 + ks1;  // k = 512+c  (v half)
        *(short8*)(raw + (((t_ * 32 + ks1) << 10) | (l << 4))) = v2p;
        *(short8*)(raw + (((t_ * 32 + ks2) << 10) | (l << 4))) = vp;
      }
      red0[part * 32 + px] = s2;
    }
    __syncthreads();
    if (tid < 32) {
      float ss = 0.f;
#pragma unroll
      for (int i = 0; i < 8; i++) ss += red0[i * 32 + tid];
      float rn = 1.f / fmaxf(sqrtf(ss), 1e-12f);  // l2_normalize -> epilogue scalars
      rnA[tid] = rn;
      rn2A[tid] = rn * rn;
    }
    __syncthreads();

    // ---- MFMA: wave = (khalf, phalf), 3 p-tiles x 2 px-tiles ----
    float4v acc[3][2] = {{}, {}, {}};
    const short* wrow = wbf + (((pbase * 16 + lm) << 10) + (khalf << 9) + (lk << 3));
#pragma unroll 4
    for (int ksl = 0; ksl < 16; ksl++) {
      const int ks = khalf * 16 + ksl;
      short8 a0 = *(const short8*)(wrow + ksl * 32);
      short8 a1 = *(const short8*)(wrow + 16384 + ksl * 32);
      short8 a2 = *(const short8*)(wrow + 32768 + ksl * 32);
      short8 b0 = *(const short8*)(raw + ((ks << 10) | (lane << 4)));
      short8 b1 = *(const short8*)(raw + (((32 + ks) << 10) | (lane << 4)));
      acc[0][0] = __builtin_amdgcn_mfma_f32_16x16x32_bf16(a0, b0, acc[0][0], 0, 0, 0);
      acc[0][1] = __builtin_amdgcn_mfma_f32_16x16x32_bf16(a0, b1, acc[0][1], 0, 0, 0);
      acc[1][0] = __builtin_amdgcn_mfma_f32_16x16x32_bf16(a1, b0, acc[1][0], 0, 0, 0);
      acc[1][1] = __builtin_amdgcn_mfma_f32_16x16x32_bf16(a1, b1, acc[1][1], 0, 0, 0);
      acc[2][0] = __builtin_amdgcn_mfma_f32_16x16x32_bf16(a2, b0, acc[2][0], 0, 0, 0);
      acc[2][1] = __builtin_amdgcn_mfma_f32_16x16x32_bf16(a2, b1, acc[2][1], 0, 0, 0);
    }

    // ---- issue next tile's x-loads (pinned after the A-stream) ----
    __builtin_amdgcn_sched_barrier(0);
    if (t + 1 < TILES_) {
      const int n0n = (blockIdx.x + GRID_ * (t + 1)) * TPX;
      const int bn = n0n >> 14, remn = n0n & 16383, hn = remn >> 7, w0n = remn & 127;
      const float* xpn = x + (size_t)bn * C_ * HW_ + hn * 128 + w0n + px;
#pragma unroll
      for (int i = 0; i < 64; i++) xr[i] = xpn[(size_t)(cbase + i) * HW_];
    }
    __builtin_amdgcn_sched_barrier(0);

    __syncthreads();  // u dead; alias raw as lp[32][100] (stride 100: bank-clean)
    float* lp = (float*)raw;

    // stage 1: a1 waves write -0.5*rn2*a1 + ct  (cts from LDS: no vmem)
    if (khalf == 0) {
#pragma unroll
      for (int i = 0; i < 3; i++) {
        const int prow = (pbase + i) * 16 + lk * 4;
#pragma unroll
        for (int r = 0; r < 4; r++) {
          const float ct = cts[prow + r];
#pragma unroll
          for (int t2 = 0; t2 < 2; t2++) {
            const int pxx = t2 * 16 + lm;
            lp[pxx * 100 + prow + r] = fmaf(-0.5f * rn2A[pxx], acc[i][t2][r], ct);
          }
        }
      }
    }
    __syncthreads();
    // stage 2: a2 waves add rn*a2
    if (khalf == 1) {
#pragma unroll
      for (int i = 0; i < 3; i++) {
        const int prow = (pbase + i) * 16 + lk * 4;
#pragma unroll
        for (int r = 0; r < 4; r++) {
#pragma unroll
          for (int t2 = 0; t2 < 2; t2++) {
            const int pxx = t2 * 16 + lm;
            lp[pxx * 100 + prow + r] += rnA[pxx] * acc[i][t2][r];
          }
        }
      }
    }
    __syncthreads();

    // ---- max over M ----
    for (int idx = tid; idx < TPX * K_; idx += 256) {
      const int pxx = idx / K_;
      const int k = idx - pxx * K_;
      const float* row = lp + pxx * 100 + k * M_;
      float mv = row[0];
#pragma unroll
      for (int m = 1; m < M_; m++) mv = fmaxf(mv, row[m]);
      mpr[pxx * 20 + k] = mv;
    }
    __syncthreads();
    // ---- LN over K (two-pass: values ~ -470, var ~ 1e-3) ----
    if (tid < 32) {
      float ss = 0.f;
      for (int k = 0; k < K_; k++) ss += mpr[tid * 20 + k];
      float m2 = ss * (1.f / K_);
      float qq = 0.f;
      for (int k = 0; k < K_; k++) {
        float d = mpr[tid * 20 + k] - m2;
        qq += d * d;
      }
      mean2A[tid] = m2;
      rstd2A[tid] = rsqrtf(qq * (1.f / K_) + 1e-5f);
    }
    __syncthreads();
    // ---- coalesced store (B,K,H,W); mgs/mbs from LDS (no vmem reads) ----
    float* obase = out + ((size_t)(b * K_) * 128 + h) * 128 + w0;
    for (int idx = tid; idx < TPX * K_; idx += 256) {
      const int k = idx >> 5, pxx = idx & 31;
      float v = fmaf((mpr[pxx * 20 + k] - mean2A[pxx]) * rstd2A[pxx], mgs[k], mbs[k]);
      obase[(size_t)k * HW_ + pxx] = v;
    }
    __syncthreads();  // protect raw/stat arrays before next tile's phases
  }
}

extern "C" void kernel_launch(void* const* d_in, const int* in_sizes, int n_in,
                              void* d_out, int out_size, void* d_ws, size_t ws_size,
                              hipStream_t stream) {
  const float* x = (const float*)d_in[0];
  const float* means = (const float*)d_in[1];
  const float* diag = (const float*)d_in[2];
  const float* fg = (const float*)d_in[3];
  const float* fb = (const float*)d_in[4];
  const float* mg = (const float*)d_in[5];
  const float* mb = (const float*)d_in[6];
  float* out = (float*)d_out;

  short* wbf = (short*)d_ws;                                     // 96*1024*2 B
  float* cterm = (float*)((char*)d_ws + (size_t)P2 * 1024 * 2);  // +96*4 B

  prep_kernel<<<P2, 256, 0, stream>>>(means, diag, wbf, cterm);
  main_kernel<<<GRID_, 256, 0, stream>>>(x, fg, fb, mg, mb, wbf, cterm, out);
}

// Round 6
// 81.628 us; speedup vs baseline: 1.5463x; 1.1933x over previous
//
#include <hip/hip_runtime.h>
#include <math.h>

#define C_ 512
#define HW_ 16384
#define K_ 19
#define M_ 5
#define P_ 95
#define P2 96
#define TPX 32
#define NBLK 2048
#define HL2PI 470.49652900081467f  // 0.5 * 512 * ln(2*pi)

typedef __attribute__((ext_vector_type(8))) short short8;
typedef __attribute__((ext_vector_type(4))) float float4v;

// fp32 -> bf16 RNE, returned as raw short
static __device__ __forceinline__ short f2bf(float f) {
  unsigned u = __builtin_bit_cast(unsigned, f);
  unsigned r = (u + 0x7fffu + ((u >> 16) & 1u)) >> 16;
  return (short)r;
}

// square a bf16x8 fragment in-register (unpack -> f32 mul -> RNE repack)
static __device__ __forceinline__ short8 sq8(short8 a) {
  short8 r;
#pragma unroll
  for (int j = 0; j < 8; j++) {
    float f = __builtin_bit_cast(float, ((unsigned)(unsigned short)a[j]) << 16);
    r[j] = f2bf(f * f);
  }
  return r;
}

__device__ __forceinline__ float block_reduce_sum(float v, volatile float* red) {
#pragma unroll
  for (int o = 32; o; o >>= 1) v += __shfl_down(v, o);
  const int lane = threadIdx.x & 63, wv = threadIdx.x >> 6;
  if (lane == 0) red[wv] = v;
  __syncthreads();
  float r = red[0] + red[1] + red[2] + red[3];
  __syncthreads();
  return r;
}

// One block per prototype p. wbf[p][k] bf16 row-major [96][1024]:
//   k <  512: inv_var[c];  k >= 512: mu[c]*inv_var[c]
// cterm[p] = -0.5*q3 - logdet - HL2PI  (fp32)
__global__ __launch_bounds__(256) void prep_kernel(
    const float* __restrict__ means, const float* __restrict__ diag,
    short* __restrict__ wbf, float* __restrict__ cterm) {
  const int p = blockIdx.x;
  const int tid = threadIdx.x;
  __shared__ float red[4];
  if (p >= P_) {  // zero-pad row 95: contributes 0, never selected in max
    for (int c = tid; c < C_; c += 256) {
      wbf[p * 1024 + c] = 0;
      wbf[p * 1024 + 512 + c] = 0;
    }
    if (tid == 0) cterm[p] = 0.f;
    return;
  }
  const float* mrow = means + (size_t)p * C_;
  const float* srow = diag + (size_t)p * C_;
  float m0 = mrow[tid], m1 = mrow[tid + 256];
  float ss = block_reduce_sum(m0 * m0 + m1 * m1, red);
  float rden = 1.f / fmaxf(sqrtf(ss), 1e-12f);  // l2_normalize(means)
  float q3 = 0.f, ld = 0.f;
#pragma unroll
  for (int t = 0; t < 2; t++) {
    int c = tid + t * 256;
    float m = mrow[c], s = srow[c];
    float mu = m * rden;
    float iv = 1.f / (s * s);
    wbf[p * 1024 + c] = f2bf(iv);
    wbf[p * 1024 + 512 + c] = f2bf(mu * iv);
    q3 += mu * mu * iv;
    ld += logf(s);
  }
  q3 = block_reduce_sum(q3, red);
  ld = block_reduce_sum(ld, red);
  if (tid == 0) cterm[p] = -0.5f * q3 - ld - HL2PI;
}

// One block = 32 pixels, 256 threads (4 waves). LDS ~38 KB -> 4 blocks/CU.
// u LDS (32 KiB, v only): 32 blocks of 1 KiB; block (t_, ks) holds
// v[k=ks*32 + (l>>4)*8 + j][px=t_*16 + (l&15)] at byte l*16 + j*2.
// q1 (v^2 . iv) B-operand is squared in-register from the v fragments.
__global__ __launch_bounds__(256) void main_kernel(
    const float* __restrict__ x,
    const float* __restrict__ fg, const float* __restrict__ fb,
    const float* __restrict__ mg, const float* __restrict__ mb,
    const short* __restrict__ wbf, const float* __restrict__ cterm,
    float* __restrict__ out) {
  __shared__ __align__(16) char raw[32768];  // u (v frags); aliased as lp[32][100]
  __shared__ float red0[8 * TPX], red1[8 * TPX];
  __shared__ float meanA[TPX], rstdA[TPX], rnA[TPX], rn2A[TPX];
  __shared__ float mean2A[TPX], rstd2A[TPX];
  __shared__ float mpr[TPX * 20];

  const int tid = threadIdx.x;
  const int px = tid & 31, part = tid >> 5;  // 8 parts x 64 channels
  const int wv = tid >> 6, lane = tid & 63;
  const int n0 = blockIdx.x * TPX;
  const int b = n0 >> 14;
  const int rem = n0 & 16383;
  const int h = rem >> 7;
  const int w0 = rem & 127;
  const int cbase = part * 64;
  const float* xp = x + (size_t)b * C_ * HW_ + h * 128 + w0 + px;

  // ---- Phase A: stream x (HBM), LN stats; no register caching ----
  {
    float s = 0.f, q = 0.f;
#pragma unroll 1
    for (int t16 = 0; t16 < 4; t16++) {
      float xv[16];
#pragma unroll
      for (int i = 0; i < 16; i++) xv[i] = xp[(size_t)(cbase + t16 * 16 + i) * HW_];
#pragma unroll
      for (int i = 0; i < 16; i++) {
        s += xv[i];
        q += xv[i] * xv[i];
      }
    }
    red0[part * 32 + px] = s;
    red1[part * 32 + px] = q;
  }
  __syncthreads();
  if (tid < 32) {
    float ss = 0.f, qq = 0.f;
#pragma unroll
    for (int i = 0; i < 8; i++) {
      ss += red0[i * 32 + tid];
      qq += red1[i * 32 + tid];
    }
    float mean = ss * (1.f / C_);
    float var = qq * (1.f / C_) - mean * mean;
    meanA[tid] = mean;
    rstdA[tid] = rsqrtf(var + 1e-5f);
  }
  __syncthreads();

  // ---- Phase B: re-read x (L2-hot), v = LN(x)*g+b, v bf16 -> LDS, sum v^2 ----
  {
    const float mean = meanA[px], rstd = rstdA[px];
    float s2 = 0.f;
    const int t_ = px >> 4;
    const int lq = px & 15;
#pragma unroll 2
    for (int t8 = 0; t8 < 8; t8++) {
      const int c0 = cbase + t8 * 8;
      float xv[8];
#pragma unroll
      for (int j = 0; j < 8; j++) xv[j] = xp[(size_t)(c0 + j) * HW_];
      short8 vp;
#pragma unroll
      for (int j = 0; j < 8; j++) {
        float v = fmaf((xv[j] - mean) * rstd, fg[c0 + j], fb[c0 + j]);
        s2 += v * v;
        vp[j] = f2bf(v);
      }
      // u block = t_*16 + (c0>>5); chunk bits = (c0>>3)&3; lane slot = lq
      *(short8*)(raw + (((t_ * 16 + (c0 >> 5)) << 10) | (((c0 >> 3) & 3) << 8) | (lq << 4))) = vp;
    }
    red0[part * 32 + px] = s2;
  }
  __syncthreads();
  if (tid < 32) {
    float ss = 0.f;
#pragma unroll
    for (int i = 0; i < 8; i++) ss += red0[i * 32 + tid];
    float rn = 1.f / fmaxf(sqrtf(ss), 1e-12f);  // l2_normalize folded into epilogue
    rnA[tid] = rn;
    rn2A[tid] = rn * rn;
  }
  __syncthreads();

  // ---- MFMA: wave = (khalf = wv>>1, phalf = wv&1), 3 p-tiles x 2 px-tiles ----
  // khalf=0: B = square(v-frag) (q1, A=iv rows); khalf=1: B = v-frag (q2, A=mu*iv)
  const int pbase = (wv & 1) * 3;
  const int khalf = wv >> 1;
  const int lm = lane & 15, lk = lane >> 4;
  float4v acc[3][2] = {{}, {}, {}};
  const short* wrow = wbf + (((pbase * 16 + lm) << 10) + (khalf << 9) + (lk << 3));
#pragma unroll 4
  for (int ksl = 0; ksl < 16; ksl++) {
    short8 a0 = *(const short8*)(wrow + ksl * 32);
    short8 a1 = *(const short8*)(wrow + 16384 + ksl * 32);
    short8 a2 = *(const short8*)(wrow + 32768 + ksl * 32);
    short8 b0 = *(const short8*)(raw + ((ksl << 10) | (lane << 4)));
    short8 b1 = *(const short8*)(raw + (((16 + ksl) << 10) | (lane << 4)));
    if (khalf == 0) {  // wave-uniform branch
      b0 = sq8(b0);
      b1 = sq8(b1);
    }
    acc[0][0] = __builtin_amdgcn_mfma_f32_16x16x32_bf16(a0, b0, acc[0][0], 0, 0, 0);
    acc[0][1] = __builtin_amdgcn_mfma_f32_16x16x32_bf16(a0, b1, acc[0][1], 0, 0, 0);
    acc[1][0] = __builtin_amdgcn_mfma_f32_16x16x32_bf16(a1, b0, acc[1][0], 0, 0, 0);
    acc[1][1] = __builtin_amdgcn_mfma_f32_16x16x32_bf16(a1, b1, acc[1][1], 0, 0, 0);
    acc[2][0] = __builtin_amdgcn_mfma_f32_16x16x32_bf16(a2, b0, acc[2][0], 0, 0, 0);
    acc[2][1] = __builtin_amdgcn_mfma_f32_16x16x32_bf16(a2, b1, acc[2][1], 0, 0, 0);
  }
  __syncthreads();  // u dead; alias raw as lp[32][100]
  float* lp = (float*)raw;

  // stage 1: khalf0 waves write -0.5*rn2*q1 + ct
  if (khalf == 0) {
#pragma unroll
    for (int i = 0; i < 3; i++) {
      const int prow = (pbase + i) * 16 + lk * 4;
#pragma unroll
      for (int r = 0; r < 4; r++) {
        const float ct = cterm[prow + r];
#pragma unroll
        for (int t2 = 0; t2 < 2; t2++) {
          const int pxx = t2 * 16 + lm;
          lp[pxx * 100 + prow + r] = fmaf(-0.5f * rn2A[pxx], acc[i][t2][r], ct);
        }
      }
    }
  }
  __syncthreads();
  // stage 2: khalf1 waves add rn*q2
  if (khalf == 1) {
#pragma unroll
    for (int i = 0; i < 3; i++) {
      const int prow = (pbase + i) * 16 + lk * 4;
#pragma unroll
      for (int r = 0; r < 4; r++) {
#pragma unroll
        for (int t2 = 0; t2 < 2; t2++) {
          const int pxx = t2 * 16 + lm;
          lp[pxx * 100 + prow + r] += rnA[pxx] * acc[i][t2][r];
        }
      }
    }
  }
  __syncthreads();

  // ---- max over M ----
  for (int idx = tid; idx < TPX * K_; idx += 256) {
    const int pxx = idx / K_;
    const int k = idx - pxx * K_;
    const float* row = lp + pxx * 100 + k * M_;
    float mv = row[0];
#pragma unroll
    for (int m = 1; m < M_; m++) mv = fmaxf(mv, row[m]);
    mpr[pxx * 20 + k] = mv;
  }
  __syncthreads();
  // ---- LN over K (two-pass: values ~ -470, var ~ 1e-3) ----
  if (tid < 32) {
    float ss = 0.f;
    for (int k = 0; k < K_; k++) ss += mpr[tid * 20 + k];
    float m2 = ss * (1.f / K_);
    float qq = 0.f;
    for (int k = 0; k < K_; k++) {
      float d = mpr[tid * 20 + k] - m2;
      qq += d * d;
    }
    mean2A[tid] = m2;
    rstd2A[tid] = rsqrtf(qq * (1.f / K_) + 1e-5f);
  }
  __syncthreads();
  // ---- coalesced store (B,K,H,W) ----
  float* obase = out + ((size_t)(b * K_) * 128 + h) * 128 + w0;
  for (int idx = tid; idx < TPX * K_; idx += 256) {
    const int k = idx >> 5, pxx = idx & 31;
    float v = fmaf((mpr[pxx * 20 + k] - mean2A[pxx]) * rstd2A[pxx], mg[k], mb[k]);
    obase[(size_t)k * HW_ + pxx] = v;
  }
}

extern "C" void kernel_launch(void* const* d_in, const int* in_sizes, int n_in,
                              void* d_out, int out_size, void* d_ws, size_t ws_size,
                              hipStream_t stream) {
  const float* x = (const float*)d_in[0];
  const float* means = (const float*)d_in[1];
  const float* diag = (const float*)d_in[2];
  const float* fg = (const float*)d_in[3];
  const float* fb = (const float*)d_in[4];
  const float* mg = (const float*)d_in[5];
  const float* mb = (const float*)d_in[6];
  float* out = (float*)d_out;

  short* wbf = (short*)d_ws;                                     // 96*1024*2 B
  float* cterm = (float*)((char*)d_ws + (size_t)P2 * 1024 * 2);  // +96*4 B

  prep_kernel<<<P2, 256, 0, stream>>>(means, diag, wbf, cterm);
  main_kernel<<<NBLK, 256, 0, stream>>>(x, fg, fb, mg, mb, wbf, cterm, out);
}

// Round 7
// 75.596 us; speedup vs baseline: 1.6697x; 1.0798x over previous
//
#include <hip/hip_runtime.h>
#include <math.h>

#define C_ 512
#define HW_ 16384
#define K_ 19
#define M_ 5
#define P_ 95
#define P2 96
#define TPX 32
#define NBLK 2048
#define HL2PI 470.49652900081467f  // 0.5 * 512 * ln(2*pi)

typedef __attribute__((ext_vector_type(8))) short short8;
typedef __attribute__((ext_vector_type(4))) float float4v;

// fp32 -> bf16 RNE, returned as raw short
static __device__ __forceinline__ short f2bf(float f) {
  unsigned u = __builtin_bit_cast(unsigned, f);
  unsigned r = (u + 0x7fffu + ((u >> 16) & 1u)) >> 16;
  return (short)r;
}
static __device__ __forceinline__ float bf2f(short s) {
  return __builtin_bit_cast(float, ((unsigned)(unsigned short)s) << 16);
}

// square a bf16x8 fragment in-register (unpack -> f32 mul -> RNE repack)
static __device__ __forceinline__ short8 sq8(short8 a) {
  short8 r;
#pragma unroll
  for (int j = 0; j < 8; j++) {
    float f = bf2f(a[j]);
    r[j] = f2bf(f * f);
  }
  return r;
}

__device__ __forceinline__ float block_reduce_sum(float v, volatile float* red) {
#pragma unroll
  for (int o = 32; o; o >>= 1) v += __shfl_down(v, o);
  const int lane = threadIdx.x & 63, wv = threadIdx.x >> 6;
  if (lane == 0) red[wv] = v;
  __syncthreads();
  float r = red[0] + red[1] + red[2] + red[3];
  __syncthreads();
  return r;
}

// One block per prototype p. wbf[p][k] bf16 row-major [96][1024]:
//   k <  512: inv_var[c];  k >= 512: mu[c]*inv_var[c]
// cterm[p] = -0.5*q3 - logdet - HL2PI  (fp32)
__global__ __launch_bounds__(256) void prep_kernel(
    const float* __restrict__ means, const float* __restrict__ diag,
    short* __restrict__ wbf, float* __restrict__ cterm) {
  const int p = blockIdx.x;
  const int tid = threadIdx.x;
  __shared__ float red[4];
  if (p >= P_) {  // zero-pad row 95: contributes 0, never selected in max
    for (int c = tid; c < C_; c += 256) {
      wbf[p * 1024 + c] = 0;
      wbf[p * 1024 + 512 + c] = 0;
    }
    if (tid == 0) cterm[p] = 0.f;
    return;
  }
  const float* mrow = means + (size_t)p * C_;
  const float* srow = diag + (size_t)p * C_;
  float m0 = mrow[tid], m1 = mrow[tid + 256];
  float ss = block_reduce_sum(m0 * m0 + m1 * m1, red);
  float rden = 1.f / fmaxf(sqrtf(ss), 1e-12f);  // l2_normalize(means)
  float q3 = 0.f, ld = 0.f;
#pragma unroll
  for (int t = 0; t < 2; t++) {
    int c = tid + t * 256;
    float m = mrow[c], s = srow[c];
    float mu = m * rden;
    float iv = 1.f / (s * s);
    wbf[p * 1024 + c] = f2bf(iv);
    wbf[p * 1024 + 512 + c] = f2bf(mu * iv);
    q3 += mu * mu * iv;
    ld += logf(s);
  }
  q3 = block_reduce_sum(q3, red);
  ld = block_reduce_sum(ld, red);
  if (tid == 0) cterm[p] = -0.5f * q3 - ld - HL2PI;
}

// One block = 32 pixels, 256 threads (4 waves). LDS ~38 KB -> 4 blocks/CU.
// Single HBM pass: phase A loads x, computes LN stats (fp32), and stages x as
// bf16 in the u fragment layout. Phase B rewrites the same bytes in-place with
// v = LN(x)*g+b (each thread touches only its own fragments -> race-free).
// u layout: 32 blocks of 1 KiB; elem (k, px) at ((t_*16+ks)<<10)|(l<<4)|(j<<1),
// l = ((k>>3)&3)<<4 | (px&15), t_ = px>>4, j = k&7.
// q1's B-operand (v^2) is squared in-register from the v fragments (khalf=0).
__global__ __launch_bounds__(256) void main_kernel(
    const float* __restrict__ x,
    const float* __restrict__ fg, const float* __restrict__ fb,
    const float* __restrict__ mg, const float* __restrict__ mb,
    const short* __restrict__ wbf, const float* __restrict__ cterm,
    float* __restrict__ out) {
  __shared__ __align__(16) char raw[32768];  // x/v frags; aliased as lp[32][100]
  __shared__ float red0[8 * TPX], red1[8 * TPX];
  __shared__ float meanA[TPX], rstdA[TPX], rnA[TPX], rn2A[TPX];
  __shared__ float mean2A[TPX], rstd2A[TPX];
  __shared__ float mpr[TPX * 20];

  const int tid = threadIdx.x;
  const int px = tid & 31, part = tid >> 5;  // 8 parts x 64 channels
  const int wv = tid >> 6, lane = tid & 63;
  const int n0 = blockIdx.x * TPX;
  const int b = n0 >> 14;
  const int rem = n0 & 16383;
  const int h = rem >> 7;
  const int w0 = rem & 127;
  const int cbase = part * 64;
  const int t_ = px >> 4, lq = px & 15;
  const float* xp = x + (size_t)b * C_ * HW_ + h * 128 + w0 + px;

  // ---- Phase A: single HBM pass; stats (fp32) + stage bf16 x into LDS ----
  {
    float s = 0.f, q = 0.f;
#pragma unroll 1
    for (int t32 = 0; t32 < 2; t32++) {
      float xv[32];
#pragma unroll
      for (int i = 0; i < 32; i++) xv[i] = xp[(size_t)(cbase + t32 * 32 + i) * HW_];
#pragma unroll
      for (int t8 = 0; t8 < 4; t8++) {
        short8 xpk;
#pragma unroll
        for (int j = 0; j < 8; j++) {
          float v = xv[t8 * 8 + j];
          s += v;
          q += v * v;
          xpk[j] = f2bf(v);
        }
        const int c0 = cbase + t32 * 32 + t8 * 8;
        *(short8*)(raw + (((t_ * 16 + (c0 >> 5)) << 10) | (((c0 >> 3) & 3) << 8) | (lq << 4))) = xpk;
      }
    }
    red0[part * 32 + px] = s;
    red1[part * 32 + px] = q;
  }
  __syncthreads();
  if (tid < 32) {
    float ss = 0.f, qq = 0.f;
#pragma unroll
    for (int i = 0; i < 8; i++) {
      ss += red0[i * 32 + tid];
      qq += red1[i * 32 + tid];
    }
    float mean = ss * (1.f / C_);
    float var = qq * (1.f / C_) - mean * mean;
    meanA[tid] = mean;
    rstdA[tid] = rsqrtf(var + 1e-5f);
  }
  __syncthreads();

  // ---- Phase B: in-place x -> v (LDS read-modify-write, own bytes only) ----
  {
    const float mean = meanA[px], rstd = rstdA[px];
    float s2 = 0.f;
#pragma unroll 2
    for (int t8 = 0; t8 < 8; t8++) {
      const int c0 = cbase + t8 * 8;
      char* addr = raw + (((t_ * 16 + (c0 >> 5)) << 10) | (((c0 >> 3) & 3) << 8) | (lq << 4));
      short8 x8 = *(short8*)addr;
      short8 vp;
#pragma unroll
      for (int j = 0; j < 8; j++) {
        float v = fmaf((bf2f(x8[j]) - mean) * rstd, fg[c0 + j], fb[c0 + j]);
        s2 += v * v;
        vp[j] = f2bf(v);
      }
      *(short8*)addr = vp;
    }
    red0[part * 32 + px] = s2;
  }
  __syncthreads();
  if (tid < 32) {
    float ss = 0.f;
#pragma unroll
    for (int i = 0; i < 8; i++) ss += red0[i * 32 + tid];
    float rn = 1.f / fmaxf(sqrtf(ss), 1e-12f);  // l2_normalize folded into epilogue
    rnA[tid] = rn;
    rn2A[tid] = rn * rn;
  }
  __syncthreads();

  // ---- MFMA: wave = (khalf = wv>>1, phalf = wv&1), 3 p-tiles x 2 px-tiles ----
  // khalf=0: B = square(v-frag) (q1, A=iv rows); khalf=1: B = v-frag (q2, A=mu*iv)
  const int pbase = (wv & 1) * 3;
  const int khalf = wv >> 1;
  const int lm = lane & 15, lk = lane >> 4;
  float4v acc[3][2] = {{}, {}, {}};
  const short* wrow = wbf + (((pbase * 16 + lm) << 10) + (khalf << 9) + (lk << 3));
#pragma unroll 4
  for (int ksl = 0; ksl < 16; ksl++) {
    short8 a0 = *(const short8*)(wrow + ksl * 32);
    short8 a1 = *(const short8*)(wrow + 16384 + ksl * 32);
    short8 a2 = *(const short8*)(wrow + 32768 + ksl * 32);
    short8 b0 = *(const short8*)(raw + ((ksl << 10) | (lane << 4)));
    short8 b1 = *(const short8*)(raw + (((16 + ksl) << 10) | (lane << 4)));
    if (khalf == 0) {  // wave-uniform branch
      b0 = sq8(b0);
      b1 = sq8(b1);
    }
    acc[0][0] = __builtin_amdgcn_mfma_f32_16x16x32_bf16(a0, b0, acc[0][0], 0, 0, 0);
    acc[0][1] = __builtin_amdgcn_mfma_f32_16x16x32_bf16(a0, b1, acc[0][1], 0, 0, 0);
    acc[1][0] = __builtin_amdgcn_mfma_f32_16x16x32_bf16(a1, b0, acc[1][0], 0, 0, 0);
    acc[1][1] = __builtin_amdgcn_mfma_f32_16x16x32_bf16(a1, b1, acc[1][1], 0, 0, 0);
    acc[2][0] = __builtin_amdgcn_mfma_f32_16x16x32_bf16(a2, b0, acc[2][0], 0, 0, 0);
    acc[2][1] = __builtin_amdgcn_mfma_f32_16x16x32_bf16(a2, b1, acc[2][1], 0, 0, 0);
  }
  __syncthreads();  // u dead; alias raw as lp[32][100]
  float* lp = (float*)raw;

  // stage 1: khalf0 waves write -0.5*rn2*q1 + ct
  if (khalf == 0) {
#pragma unroll
    for (int i = 0; i < 3; i++) {
      const int prow = (pbase + i) * 16 + lk * 4;
#pragma unroll
      for (int r = 0; r < 4; r++) {
        const float ct = cterm[prow + r];
#pragma unroll
        for (int t2 = 0; t2 < 2; t2++) {
          const int pxx = t2 * 16 + lm;
          lp[pxx * 100 + prow + r] = fmaf(-0.5f * rn2A[pxx], acc[i][t2][r], ct);
        }
      }
    }
  }
  __syncthreads();
  // stage 2: khalf1 waves add rn*q2
  if (khalf == 1) {
#pragma unroll
    for (int i = 0; i < 3; i++) {
      const int prow = (pbase + i) * 16 + lk * 4;
#pragma unroll
      for (int r = 0; r < 4; r++) {
#pragma unroll
        for (int t2 = 0; t2 < 2; t2++) {
          const int pxx = t2 * 16 + lm;
          lp[pxx * 100 + prow + r] += rnA[pxx] * acc[i][t2][r];
        }
      }
    }
  }
  __syncthreads();

  // ---- max over M ----
  for (int idx = tid; idx < TPX * K_; idx += 256) {
    const int pxx = idx / K_;
    const int k = idx - pxx * K_;
    const float* row = lp + pxx * 100 + k * M_;
    float mv = row[0];
#pragma unroll
    for (int m = 1; m < M_; m++) mv = fmaxf(mv, row[m]);
    mpr[pxx * 20 + k] = mv;
  }
  __syncthreads();
  // ---- LN over K (two-pass: values ~ -470, var ~ 1e-3) ----
  if (tid < 32) {
    float ss = 0.f;
    for (int k = 0; k < K_; k++) ss += mpr[tid * 20 + k];
    float m2 = ss * (1.f / K_);
    float qq = 0.f;
    for (int k = 0; k < K_; k++) {
      float d = mpr[tid * 20 + k] - m2;
      qq += d * d;
    }
    mean2A[tid] = m2;
    rstd2A[tid] = rsqrtf(qq * (1.f / K_) + 1e-5f);
  }
  __syncthreads();
  // ---- coalesced store (B,K,H,W) ----
  float* obase = out + ((size_t)(b * K_) * 128 + h) * 128 + w0;
  for (int idx = tid; idx < TPX * K_; idx += 256) {
    const int k = idx >> 5, pxx = idx & 31;
    float v = fmaf((mpr[pxx * 20 + k] - mean2A[pxx]) * rstd2A[pxx], mg[k], mb[k]);
    obase[(size_t)k * HW_ + pxx] = v;
  }
}

extern "C" void kernel_launch(void* const* d_in, const int* in_sizes, int n_in,
                              void* d_out, int out_size, void* d_ws, size_t ws_size,
                              hipStream_t stream) {
  const float* x = (const float*)d_in[0];
  const float* means = (const float*)d_in[1];
  const float* diag = (const float*)d_in[2];
  const float* fg = (const float*)d_in[3];
  const float* fb = (const float*)d_in[4];
  const float* mg = (const float*)d_in[5];
  const float* mb = (const float*)d_in[6];
  float* out = (float*)d_out;

  short* wbf = (short*)d_ws;                                     // 96*1024*2 B
  float* cterm = (float*)((char*)d_ws + (size_t)P2 * 1024 * 2);  // +96*4 B

  prep_kernel<<<P2, 256, 0, stream>>>(means, diag, wbf, cterm);
  main_kernel<<<NBLK, 256, 0, stream>>>(x, fg, fb, mg, mb, wbf, cterm, out);
}